// Round 10
// baseline (8802.228 us; speedup 1.0000x reference)
//
#include <hip/hip_runtime.h>
#include <hip/hip_bf16.h>
#include <math.h>

// Problem constants (match reference)
#define V_ 32000
#define D_ 1024
#define E_ 8
#define H_ 4096
#define T_ 2048
#define NHOPS_ 4
#define K_ 2
#define EPS_ 1e-5f

#define LDW 40  // padded LDS row stride in ushorts (80 B -> ~2-way bank conflicts, free)

typedef __attribute__((ext_vector_type(8))) short short8v;
typedef __attribute__((ext_vector_type(4))) float f32x4;

__device__ __forceinline__ unsigned short f2bf(float f) {
  union { float f; unsigned u; } v;
  v.f = f;
  unsigned r = v.u + 0x7FFF + ((v.u >> 16) & 1);  // RNE
  return (unsigned short)(r >> 16);
}
__device__ __forceinline__ float bf2f(unsigned short b) {
  union { unsigned u; float f; } v;
  v.u = ((unsigned)b) << 16;
  return v.f;
}
// split-bf16: v ~= hi + lo (~2^-17 rel). Expert path must stay near-f32 so
// downstream top-2 routing decisions do not flip vs the f32 reference.
__device__ __forceinline__ void split_bf(float v, unsigned short& hi, unsigned short& lo) {
  hi = f2bf(v);
  lo = f2bf(v - bf2f(hi));
}

__device__ __forceinline__ float gelu_f(float x) {
  float x3 = x * x * x;
  return 0.5f * x * (1.0f + tanhf(0.7978845608028654f * (x + 0.044715f * x3)));
}

// ------- once-per-launch: split W (f32 [E][R][C]) into transposed bf16 hi/lo [E][C][R] -------
__global__ void k_split_transpose(const float* __restrict__ src, unsigned short* __restrict__ dhi,
                                  unsigned short* __restrict__ dlo, int R, int C) {
  int e = blockIdx.z;
  int r0 = blockIdx.x * 64, c0 = blockIdx.y * 64;
  const float* s = src + (size_t)e * R * C;
  __shared__ float tile[64][65];
  int tid = threadIdx.x;
  int lr = tid >> 6;
  int lc = tid & 63;
#pragma unroll
  for (int p = 0; p < 16; ++p) {
    int rr = p * 4 + lr;
    tile[rr][lc] = s[(size_t)(r0 + rr) * C + c0 + lc];
  }
  __syncthreads();
  unsigned short* ph = dhi + (size_t)e * R * C;
  unsigned short* pl = dlo + (size_t)e * R * C;
#pragma unroll
  for (int p = 0; p < 16; ++p) {
    int cc = p * 4 + lr;
    float v = tile[lc][cc];
    unsigned short hi, lo;
    split_bf(v, hi, lo);
    size_t o = (size_t)(c0 + cc) * R + r0 + lc;
    ph[o] = hi;
    pl[o] = lo;
  }
}

// ---------------- gather ----------------
__global__ void k_gather(const int* __restrict__ ids, const float* __restrict__ embed,
                         float* __restrict__ h) {
  int t = blockIdx.x;
  const float4* src = (const float4*)(embed + (size_t)ids[t] * D_);
  float4* dst = (float4*)(h + (size_t)t * D_);
  dst[threadIdx.x] = src[threadIdx.x];
}

// ---------------- router (verified, f32) ----------------
__global__ void k_router(const float* __restrict__ h, const float* __restrict__ rln,
                         const float* __restrict__ rW, float* __restrict__ invr,
                         int* __restrict__ eidx, float* __restrict__ gate) {
  int t = blockIdx.x;
  int tid = threadIdx.x;
  const float* hp = h + (size_t)t * D_;
  float lacc[E_] = {0.f, 0.f, 0.f, 0.f, 0.f, 0.f, 0.f, 0.f};
  float ss = 0.f;
  for (int d = tid; d < D_; d += 256) {
    float x = hp[d];
    ss += x * x;
    float xw = x * rln[d];
    const float* wr = rW + (size_t)d * E_;
#pragma unroll
    for (int e = 0; e < E_; ++e) lacc[e] += xw * wr[e];
  }
  __shared__ float s_l[256][E_];
  __shared__ float s_ss[256];
  __shared__ float s_lg[E_];
  __shared__ float s_ir;
#pragma unroll
  for (int e = 0; e < E_; ++e) s_l[tid][e] = lacc[e];
  s_ss[tid] = ss;
  __syncthreads();
  if (tid < E_) {
    float a = 0.f;
    for (int i = 0; i < 256; ++i) a += s_l[i][tid];
    s_lg[tid] = a;
  } else if (tid == E_) {
    float tot = 0.f;
    for (int i = 0; i < 256; ++i) tot += s_ss[i];
    s_ir = rsqrtf(tot / (float)D_ + EPS_);
  }
  __syncthreads();
  if (tid == 0) {
    float ir = s_ir;
    invr[t] = ir;
    float lg[E_];
#pragma unroll
    for (int e = 0; e < E_; ++e) lg[e] = s_lg[e] * ir;
    int i0 = 0;
#pragma unroll
    for (int e = 1; e < E_; ++e)
      if (lg[e] > lg[i0]) i0 = e;
    int i1 = (i0 == 0) ? 1 : 0;
#pragma unroll
    for (int e = 0; e < E_; ++e)
      if (e != i0 && lg[e] > lg[i1]) i1 = e;
    float m = lg[0];
#pragma unroll
    for (int e = 1; e < E_; ++e) m = fmaxf(m, lg[e]);
    float den = 0.f;
#pragma unroll
    for (int e = 0; e < E_; ++e) den += expf(lg[e] - m);
    eidx[t * 2 + 0] = i0;
    eidx[t * 2 + 1] = i1;
    gate[t * 2 + 0] = expf(lg[i0] - m) / den;
    gate[t * 2 + 1] = expf(lg[i1] - m) / den;
  }
}

// ---------------- grouping (verified) ----------------
__global__ void k_zero_counts(int* counts, int* cursor) {
  if (threadIdx.x < E_) {
    counts[threadIdx.x] = 0;
    cursor[threadIdx.x] = 0;
  }
}
__global__ void k_count(const int* __restrict__ eidx, int* __restrict__ counts) {
  int i = blockIdx.x * 256 + threadIdx.x;
  if (i < T_ * K_) atomicAdd(&counts[eidx[i]], 1);
}
__global__ void k_scan(const int* __restrict__ counts, int* __restrict__ offsets) {
  if (threadIdx.x == 0) {
    int a = 0;
    for (int e = 0; e < E_; ++e) {
      offsets[e] = a;
      a += counts[e];
    }
  }
}
__global__ void k_fill(const int* __restrict__ eidx, const float* __restrict__ gate,
                       const int* __restrict__ offsets, int* __restrict__ cursor,
                       int* __restrict__ rowtok, float* __restrict__ rowgate) {
  int i = blockIdx.x * 256 + threadIdx.x;
  if (i >= T_ * K_) return;
  int e = eidx[i];
  int p = atomicAdd(&cursor[e], 1);
  int r = offsets[e] + p;
  rowtok[r] = i >> 1;
  rowgate[r] = gate[i];
}

// ------- gemm1: BM=128 BN=64 BK=32; wave(2x2) owns 64x32 = 4x2 frags; split-bf16 -------
__global__ void k_mfma_gemm1(const float* __restrict__ h, const float* __restrict__ invr,
                             const float* __restrict__ eln,
                             const unsigned short* __restrict__ W1Thi,
                             const unsigned short* __restrict__ W1Tlo,
                             const int* __restrict__ counts, const int* __restrict__ offsets,
                             const int* __restrict__ rowtok, unsigned short* __restrict__ uHi,
                             unsigned short* __restrict__ uLo) {
  int e = blockIdx.z;
  int cnt = counts[e];
  int m0 = blockIdx.x * 128;
  if (m0 >= cnt) return;
  int n0 = blockIdx.y * 64;
  int base = offsets[e];

  __shared__ alignas(16) unsigned short Ah[128 * LDW];
  __shared__ alignas(16) unsigned short Al[128 * LDW];
  __shared__ alignas(16) unsigned short Bh[64 * LDW];
  __shared__ alignas(16) unsigned short Bl[64 * LDW];

  int tid = threadIdx.x;
  int lane = tid & 63;
  int wid = tid >> 6;
  int wr = wid >> 1, wc = wid & 1;
  int fr = lane & 15, fs = lane >> 4;

  // A staging: 128 rows x 2 half-k per row
  int ar = tid >> 1;
  int akh = (tid & 1) * 16;
  int arow = m0 + ar;
  bool av = arow < cnt;
  int tok = 0;
  float sc = 0.f;
  if (av) {
    tok = rowtok[base + arow];
    sc = invr[tok];
  }
  const float* hA = h + (size_t)tok * D_;
  const float* elnE = eln + (size_t)e * D_;

  // B staging: 64 n-rows x 4 k-chunks of 8
  int bn = tid >> 2;
  int bkh = (tid & 3) * 8;
  const unsigned short* w1h = W1Thi + ((size_t)e * H_ + n0 + bn) * D_;
  const unsigned short* w1l = W1Tlo + ((size_t)e * H_ + n0 + bn) * D_;

  f32x4 zero4 = {0.f, 0.f, 0.f, 0.f};
  f32x4 acc[4][2];
#pragma unroll
  for (int mi = 0; mi < 4; ++mi)
#pragma unroll
    for (int nj = 0; nj < 2; ++nj) acc[mi][nj] = zero4;

  for (int k0 = 0; k0 < D_; k0 += 32) {
    {
      unsigned short ah16[16], al16[16];
      if (av) {
        const float* xp = hA + k0 + akh;
        const float* ep = elnE + k0 + akh;
#pragma unroll
        for (int q = 0; q < 16; ++q) split_bf(xp[q] * sc * ep[q], ah16[q], al16[q]);
      } else {
#pragma unroll
        for (int q = 0; q < 16; ++q) { ah16[q] = 0; al16[q] = 0; }
      }
      *(short8v*)&Ah[ar * LDW + akh] = *(const short8v*)&ah16[0];
      *(short8v*)&Ah[ar * LDW + akh + 8] = *(const short8v*)&ah16[8];
      *(short8v*)&Al[ar * LDW + akh] = *(const short8v*)&al16[0];
      *(short8v*)&Al[ar * LDW + akh + 8] = *(const short8v*)&al16[8];
    }
    *(short8v*)&Bh[bn * LDW + bkh] = *(const short8v*)(w1h + k0 + bkh);
    *(short8v*)&Bl[bn * LDW + bkh] = *(const short8v*)(w1l + k0 + bkh);
    __syncthreads();
    short8v a_h[4], a_l[4], b_h[2], b_l[2];
#pragma unroll
    for (int mi = 0; mi < 4; ++mi) {
      a_h[mi] = *(const short8v*)&Ah[(wr * 64 + mi * 16 + fr) * LDW + fs * 8];
      a_l[mi] = *(const short8v*)&Al[(wr * 64 + mi * 16 + fr) * LDW + fs * 8];
    }
#pragma unroll
    for (int nj = 0; nj < 2; ++nj) {
      b_h[nj] = *(const short8v*)&Bh[(wc * 32 + nj * 16 + fr) * LDW + fs * 8];
      b_l[nj] = *(const short8v*)&Bl[(wc * 32 + nj * 16 + fr) * LDW + fs * 8];
    }
#pragma unroll
    for (int mi = 0; mi < 4; ++mi)
#pragma unroll
      for (int nj = 0; nj < 2; ++nj) {
        acc[mi][nj] = __builtin_amdgcn_mfma_f32_16x16x32_bf16(a_h[mi], b_h[nj], acc[mi][nj], 0, 0, 0);
        acc[mi][nj] = __builtin_amdgcn_mfma_f32_16x16x32_bf16(a_h[mi], b_l[nj], acc[mi][nj], 0, 0, 0);
        acc[mi][nj] = __builtin_amdgcn_mfma_f32_16x16x32_bf16(a_l[mi], b_h[nj], acc[mi][nj], 0, 0, 0);
      }
    __syncthreads();
  }
#pragma unroll
  for (int mi = 0; mi < 4; ++mi)
#pragma unroll
    for (int i = 0; i < 4; ++i) {
      int row = m0 + wr * 64 + mi * 16 + fs * 4 + i;
      if (row < cnt) {
#pragma unroll
        for (int nj = 0; nj < 2; ++nj) {
          int col = n0 + wc * 32 + nj * 16 + fr;
          float g = gelu_f(acc[mi][nj][i]);
          unsigned short hi, lo;
          split_bf(g, hi, lo);
          size_t idx = (size_t)(base + row) * H_ + col;
          uHi[idx] = hi;
          uLo[idx] = lo;
        }
      }
    }
}

// ------- gemm2: BM=128 BN=128 BK=32; wave(2x2) owns 64x64 = 4x4 frags; split-bf16 -------
__global__ void k_mfma_gemm2(const unsigned short* __restrict__ uHi,
                             const unsigned short* __restrict__ uLo,
                             const unsigned short* __restrict__ W2Thi,
                             const unsigned short* __restrict__ W2Tlo,
                             const int* __restrict__ counts, const int* __restrict__ offsets,
                             const int* __restrict__ rowtok, const float* __restrict__ rowgate,
                             float* __restrict__ h) {
  int e = blockIdx.z;
  int cnt = counts[e];
  int m0 = blockIdx.x * 128;
  if (m0 >= cnt) return;
  int n0 = blockIdx.y * 128;
  int base = offsets[e];

  __shared__ alignas(16) unsigned short Ah[128 * LDW];
  __shared__ alignas(16) unsigned short Al[128 * LDW];
  __shared__ alignas(16) unsigned short Bh[128 * LDW];
  __shared__ alignas(16) unsigned short Bl[128 * LDW];

  int tid = threadIdx.x;
  int lane = tid & 63;
  int wid = tid >> 6;
  int wr = wid >> 1, wc = wid & 1;
  int fr = lane & 15, fs = lane >> 4;

  // A staging: 128 rows x 2 half-k
  int ar = tid >> 1;
  int akh = (tid & 1) * 16;
  int arow = m0 + ar;
  bool av = arow < cnt;
  size_t arowoff = (size_t)(base + (av ? arow : 0)) * H_;
  // B staging: 128 n-rows x 2 half-k
  const unsigned short* w2h = W2Thi + ((size_t)e * D_ + n0 + ar) * H_;
  const unsigned short* w2l = W2Tlo + ((size_t)e * D_ + n0 + ar) * H_;

  f32x4 zero4 = {0.f, 0.f, 0.f, 0.f};
  f32x4 acc[4][4];
#pragma unroll
  for (int mi = 0; mi < 4; ++mi)
#pragma unroll
    for (int nj = 0; nj < 4; ++nj) acc[mi][nj] = zero4;

  for (int k0 = 0; k0 < H_; k0 += 32) {
    if (av) {
      *(short8v*)&Ah[ar * LDW + akh] = *(const short8v*)(uHi + arowoff + k0 + akh);
      *(short8v*)&Ah[ar * LDW + akh + 8] = *(const short8v*)(uHi + arowoff + k0 + akh + 8);
      *(short8v*)&Al[ar * LDW + akh] = *(const short8v*)(uLo + arowoff + k0 + akh);
      *(short8v*)&Al[ar * LDW + akh + 8] = *(const short8v*)(uLo + arowoff + k0 + akh + 8);
    } else {
      short8v z = {0, 0, 0, 0, 0, 0, 0, 0};
      *(short8v*)&Ah[ar * LDW + akh] = z;
      *(short8v*)&Ah[ar * LDW + akh + 8] = z;
      *(short8v*)&Al[ar * LDW + akh] = z;
      *(short8v*)&Al[ar * LDW + akh + 8] = z;
    }
    *(short8v*)&Bh[ar * LDW + akh] = *(const short8v*)(w2h + k0 + akh);
    *(short8v*)&Bh[ar * LDW + akh + 8] = *(const short8v*)(w2h + k0 + akh + 8);
    *(short8v*)&Bl[ar * LDW + akh] = *(const short8v*)(w2l + k0 + akh);
    *(short8v*)&Bl[ar * LDW + akh + 8] = *(const short8v*)(w2l + k0 + akh + 8);
    __syncthreads();
    short8v a_h[4], a_l[4], b_h[4], b_l[4];
#pragma unroll
    for (int mi = 0; mi < 4; ++mi) {
      a_h[mi] = *(const short8v*)&Ah[(wr * 64 + mi * 16 + fr) * LDW + fs * 8];
      a_l[mi] = *(const short8v*)&Al[(wr * 64 + mi * 16 + fr) * LDW + fs * 8];
    }
#pragma unroll
    for (int nj = 0; nj < 4; ++nj) {
      b_h[nj] = *(const short8v*)&Bh[(wc * 64 + nj * 16 + fr) * LDW + fs * 8];
      b_l[nj] = *(const short8v*)&Bl[(wc * 64 + nj * 16 + fr) * LDW + fs * 8];
    }
#pragma unroll
    for (int mi = 0; mi < 4; ++mi)
#pragma unroll
      for (int nj = 0; nj < 4; ++nj) {
        acc[mi][nj] = __builtin_amdgcn_mfma_f32_16x16x32_bf16(a_h[mi], b_h[nj], acc[mi][nj], 0, 0, 0);
        acc[mi][nj] = __builtin_amdgcn_mfma_f32_16x16x32_bf16(a_h[mi], b_l[nj], acc[mi][nj], 0, 0, 0);
        acc[mi][nj] = __builtin_amdgcn_mfma_f32_16x16x32_bf16(a_l[mi], b_h[nj], acc[mi][nj], 0, 0, 0);
      }
    __syncthreads();
  }
#pragma unroll
  for (int mi = 0; mi < 4; ++mi)
#pragma unroll
    for (int i = 0; i < 4; ++i) {
      int row = m0 + wr * 64 + mi * 16 + fs * 4 + i;
      if (row < cnt) {
        int tok = rowtok[base + row];
        float g = rowgate[base + row];
        float* hp = h + (size_t)tok * D_;
#pragma unroll
        for (int nj = 0; nj < 4; ++nj) {
          int col = n0 + wc * 64 + nj * 16 + fr;
          atomicAdd(&hp[col], g * acc[mi][nj][i]);
        }
      }
    }
}

// ---------------- final rmsnorm -> bf16 ----------------
__global__ void k_finalnorm(const float* __restrict__ h, const float* __restrict__ w,
                            unsigned short* __restrict__ fnb) {
  int t = blockIdx.x;
  int tid = threadIdx.x;
  const float* hp = h + (size_t)t * D_;
  float ss = 0.f;
  for (int d = tid; d < D_; d += 256) {
    float x = hp[d];
    ss += x * x;
  }
  __shared__ float s[256];
  s[tid] = ss;
  __syncthreads();
  for (int o = 128; o > 0; o >>= 1) {
    if (tid < o) s[tid] += s[tid + o];
    __syncthreads();
  }
  float ir = rsqrtf(s[0] / (float)D_ + EPS_);
  for (int d = tid; d < D_; d += 256) fnb[(size_t)t * D_ + d] = f2bf(hp[d] * ir * w[d]);
}

// ------- final GEMM: BM=128 BN=64 BK=32, single bf16: out = fn . embed^T -------
__global__ void k_mfma_final(const unsigned short* __restrict__ fnb,
                             const float* __restrict__ embed, float* __restrict__ out) {
  int m0 = blockIdx.x * 128;
  int n0 = blockIdx.y * 64;

  __shared__ alignas(16) unsigned short As[128 * LDW];
  __shared__ alignas(16) unsigned short Bs[64 * LDW];

  int tid = threadIdx.x;
  int lane = tid & 63;
  int wid = tid >> 6;
  int wr = wid >> 1, wc = wid & 1;
  int fr = lane & 15, fs = lane >> 4;

  int ar = tid >> 1;
  int akh = (tid & 1) * 16;
  const unsigned short* fA = fnb + (size_t)(m0 + ar) * D_;

  int bn = tid >> 2;
  int bkh = (tid & 3) * 8;
  const float* eB = embed + (size_t)(n0 + bn) * D_;

  f32x4 zero4 = {0.f, 0.f, 0.f, 0.f};
  f32x4 acc[4][2];
#pragma unroll
  for (int mi = 0; mi < 4; ++mi)
#pragma unroll
    for (int nj = 0; nj < 2; ++nj) acc[mi][nj] = zero4;

  for (int k0 = 0; k0 < D_; k0 += 32) {
    *(short8v*)&As[ar * LDW + akh] = *(const short8v*)(fA + k0 + akh);
    *(short8v*)&As[ar * LDW + akh + 8] = *(const short8v*)(fA + k0 + akh + 8);
    {
      float4 x0 = *(const float4*)(eB + k0 + bkh);
      float4 x1 = *(const float4*)(eB + k0 + bkh + 4);
      unsigned short b8[8];
      b8[0] = f2bf(x0.x); b8[1] = f2bf(x0.y); b8[2] = f2bf(x0.z); b8[3] = f2bf(x0.w);
      b8[4] = f2bf(x1.x); b8[5] = f2bf(x1.y); b8[6] = f2bf(x1.z); b8[7] = f2bf(x1.w);
      *(short8v*)&Bs[bn * LDW + bkh] = *(const short8v*)b8;
    }
    __syncthreads();
    short8v a_[4], b_[2];
#pragma unroll
    for (int mi = 0; mi < 4; ++mi)
      a_[mi] = *(const short8v*)&As[(wr * 64 + mi * 16 + fr) * LDW + fs * 8];
#pragma unroll
    for (int nj = 0; nj < 2; ++nj)
      b_[nj] = *(const short8v*)&Bs[(wc * 32 + nj * 16 + fr) * LDW + fs * 8];
#pragma unroll
    for (int mi = 0; mi < 4; ++mi)
#pragma unroll
      for (int nj = 0; nj < 2; ++nj)
        acc[mi][nj] = __builtin_amdgcn_mfma_f32_16x16x32_bf16(a_[mi], b_[nj], acc[mi][nj], 0, 0, 0);
    __syncthreads();
  }
#pragma unroll
  for (int mi = 0; mi < 4; ++mi)
#pragma unroll
    for (int i = 0; i < 4; ++i) {
      int row = m0 + wr * 64 + mi * 16 + fs * 4 + i;
      float* op = out + (size_t)row * V_;
#pragma unroll
      for (int nj = 0; nj < 2; ++nj) {
        int col = n0 + wc * 32 + nj * 16 + fr;
        op[col] = acc[mi][nj][i];
      }
    }
}

// ---------------- launch ----------------
extern "C" void kernel_launch(void* const* d_in, const int* in_sizes, int n_in,
                              void* d_out, int out_size, void* d_ws, size_t ws_size,
                              hipStream_t stream) {
  const int* ids = (const int*)d_in[0];
  const float* embed = (const float*)d_in[1];
  const float* router_ln = (const float*)d_in[2];
  const float* router_W = (const float*)d_in[3];
  const float* expert_ln = (const float*)d_in[4];
  const float* W1 = (const float*)d_in[5];
  const float* W2 = (const float*)d_in[6];
  const float* ln_out_w = (const float*)d_in[7];
  float* out = (float*)d_out;

  char* p = (char*)d_ws;
  auto carve = [&](size_t bytes) {
    char* r = p;
    p += (bytes + 255) & ~(size_t)255;
    return (void*)r;
  };
  float* h = (float*)carve((size_t)T_ * D_ * 4);
  unsigned short* fnb = (unsigned short*)carve((size_t)T_ * D_ * 2);
  unsigned short* uHi = (unsigned short*)carve((size_t)T_ * K_ * H_ * 2);
  unsigned short* uLo = (unsigned short*)carve((size_t)T_ * K_ * H_ * 2);
  unsigned short* w1thi = (unsigned short*)carve((size_t)E_ * D_ * H_ * 2);
  unsigned short* w1tlo = (unsigned short*)carve((size_t)E_ * D_ * H_ * 2);
  unsigned short* w2thi = (unsigned short*)carve((size_t)E_ * H_ * D_ * 2);
  unsigned short* w2tlo = (unsigned short*)carve((size_t)E_ * H_ * D_ * 2);
  float* invr = (float*)carve((size_t)T_ * 4);
  int* eidx = (int*)carve((size_t)T_ * K_ * 4);
  float* gate = (float*)carve((size_t)T_ * K_ * 4);
  int* rowtok = (int*)carve((size_t)T_ * K_ * 4);
  float* rowgate = (float*)carve((size_t)T_ * K_ * 4);
  int* counts = (int*)carve(256);
  int* offsets = (int*)carve(256);
  int* cursor = (int*)carve(256);

  // once per launch: split+transpose weights (constant across hops)
  k_split_transpose<<<dim3(D_ / 64, H_ / 64, E_), 256, 0, stream>>>(W1, w1thi, w1tlo, D_, H_);
  k_split_transpose<<<dim3(H_ / 64, D_ / 64, E_), 256, 0, stream>>>(W2, w2thi, w2tlo, H_, D_);

  k_gather<<<T_, 256, 0, stream>>>(ids, embed, h);

  for (int hop = 0; hop < NHOPS_; ++hop) {
    const float* rln = router_ln + (size_t)hop * D_;
    const float* rW = router_W + (size_t)hop * D_ * E_;
    k_router<<<T_, 256, 0, stream>>>(h, rln, rW, invr, eidx, gate);
    k_zero_counts<<<1, 64, 0, stream>>>(counts, cursor);
    k_count<<<(T_ * K_) / 256, 256, 0, stream>>>(eidx, counts);
    k_scan<<<1, 64, 0, stream>>>(counts, offsets);
    k_fill<<<(T_ * K_) / 256, 256, 0, stream>>>(eidx, gate, offsets, cursor, rowtok, rowgate);
    k_mfma_gemm1<<<dim3(T_ * K_ / 128, H_ / 64, E_), 256, 0, stream>>>(
        h, invr, expert_ln, w1thi, w1tlo, counts, offsets, rowtok, uHi, uLo);
    k_mfma_gemm2<<<dim3(T_ * K_ / 128, D_ / 128, E_), 256, 0, stream>>>(
        uHi, uLo, w2thi, w2tlo, counts, offsets, rowtok, rowgate, h);
  }

  k_finalnorm<<<T_, 256, 0, stream>>>(h, ln_out_w, fnb);
  k_mfma_final<<<dim3(T_ / 128, V_ / 64), 256, 0, stream>>>(fnb, embed, out);
}

// Round 12
// 5635.608 us; speedup vs baseline: 1.5619x; 1.5619x over previous
//
#include <hip/hip_runtime.h>
#include <hip/hip_bf16.h>
#include <math.h>

// Problem constants (match reference)
#define V_ 32000
#define D_ 1024
#define E_ 8
#define H_ 4096
#define T_ 2048
#define NHOPS_ 4
#define K_ 2
#define EPS_ 1e-5f

#define LDK 40  // padded LDS row stride (ushorts) for manual-staged arrays
#define LDL 32  // linear LDS row stride for global_load_lds-staged arrays

typedef __attribute__((ext_vector_type(8))) short short8v;
typedef __attribute__((ext_vector_type(4))) float f32x4;

__device__ __forceinline__ unsigned short f2bf(float f) {
  union { float f; unsigned u; } v;
  v.f = f;
  unsigned r = v.u + 0x7FFF + ((v.u >> 16) & 1);  // RNE
  return (unsigned short)(r >> 16);
}
__device__ __forceinline__ float bf2f(unsigned short b) {
  union { unsigned u; float f; } v;
  v.u = ((unsigned)b) << 16;
  return v.f;
}
// split-bf16: v ~= hi + lo (~2^-17 rel). Expert path must stay near-f32 so
// downstream top-2 routing decisions do not flip vs the f32 reference.
__device__ __forceinline__ void split_bf(float v, unsigned short& hi, unsigned short& lo) {
  hi = f2bf(v);
  lo = f2bf(v - bf2f(hi));
}

__device__ __forceinline__ float gelu_f(float x) {
  float x3 = x * x * x;
  return 0.5f * x * (1.0f + tanhf(0.7978845608028654f * (x + 0.044715f * x3)));
}

// async global->LDS, 16B per lane; LDS dest = wave-uniform base + lane*16
__device__ __forceinline__ void gload_lds16(const void* g, void* l) {
  __builtin_amdgcn_global_load_lds((const __attribute__((address_space(1))) unsigned int*)g,
                                   (__attribute__((address_space(3))) unsigned int*)l, 16, 0, 0);
}

// ------- once-per-launch: split W (f32 [E][R][C]) into transposed bf16 hi/lo [E][C][R] -------
__global__ void k_split_transpose(const float* __restrict__ src, unsigned short* __restrict__ dhi,
                                  unsigned short* __restrict__ dlo, int R, int C) {
  int e = blockIdx.z;
  int r0 = blockIdx.x * 64, c0 = blockIdx.y * 64;
  const float* s = src + (size_t)e * R * C;
  __shared__ float tile[64][65];
  int tid = threadIdx.x;
  int lr = tid >> 6;
  int lc = tid & 63;
#pragma unroll
  for (int p = 0; p < 16; ++p) {
    int rr = p * 4 + lr;
    tile[rr][lc] = s[(size_t)(r0 + rr) * C + c0 + lc];
  }
  __syncthreads();
  unsigned short* ph = dhi + (size_t)e * R * C;
  unsigned short* pl = dlo + (size_t)e * R * C;
#pragma unroll
  for (int p = 0; p < 16; ++p) {
    int cc = p * 4 + lr;
    float v = tile[lc][cc];
    unsigned short hi, lo;
    split_bf(v, hi, lo);
    size_t o = (size_t)(c0 + cc) * R + r0 + lc;
    ph[o] = hi;
    pl[o] = lo;
  }
}

// ---------------- gather ----------------
__global__ void k_gather(const int* __restrict__ ids, const float* __restrict__ embed,
                         float* __restrict__ h) {
  int t = blockIdx.x;
  const float4* src = (const float4*)(embed + (size_t)ids[t] * D_);
  float4* dst = (float4*)(h + (size_t)t * D_);
  dst[threadIdx.x] = src[threadIdx.x];
}

// ---------------- router (verified, f32) ----------------
__global__ void k_router(const float* __restrict__ h, const float* __restrict__ rln,
                         const float* __restrict__ rW, float* __restrict__ invr,
                         int* __restrict__ eidx, float* __restrict__ gate) {
  int t = blockIdx.x;
  int tid = threadIdx.x;
  const float* hp = h + (size_t)t * D_;
  float lacc[E_] = {0.f, 0.f, 0.f, 0.f, 0.f, 0.f, 0.f, 0.f};
  float ss = 0.f;
  for (int d = tid; d < D_; d += 256) {
    float x = hp[d];
    ss += x * x;
    float xw = x * rln[d];
    const float* wr = rW + (size_t)d * E_;
#pragma unroll
    for (int e = 0; e < E_; ++e) lacc[e] += xw * wr[e];
  }
  __shared__ float s_l[256][E_];
  __shared__ float s_ss[256];
  __shared__ float s_lg[E_];
  __shared__ float s_ir;
#pragma unroll
  for (int e = 0; e < E_; ++e) s_l[tid][e] = lacc[e];
  s_ss[tid] = ss;
  __syncthreads();
  if (tid < E_) {
    float a = 0.f;
    for (int i = 0; i < 256; ++i) a += s_l[i][tid];
    s_lg[tid] = a;
  } else if (tid == E_) {
    float tot = 0.f;
    for (int i = 0; i < 256; ++i) tot += s_ss[i];
    s_ir = rsqrtf(tot / (float)D_ + EPS_);
  }
  __syncthreads();
  if (tid == 0) {
    float ir = s_ir;
    invr[t] = ir;
    float lg[E_];
#pragma unroll
    for (int e = 0; e < E_; ++e) lg[e] = s_lg[e] * ir;
    int i0 = 0;
#pragma unroll
    for (int e = 1; e < E_; ++e)
      if (lg[e] > lg[i0]) i0 = e;
    int i1 = (i0 == 0) ? 1 : 0;
#pragma unroll
    for (int e = 0; e < E_; ++e)
      if (e != i0 && lg[e] > lg[i1]) i1 = e;
    float m = lg[0];
#pragma unroll
    for (int e = 1; e < E_; ++e) m = fmaxf(m, lg[e]);
    float den = 0.f;
#pragma unroll
    for (int e = 0; e < E_; ++e) den += expf(lg[e] - m);
    eidx[t * 2 + 0] = i0;
    eidx[t * 2 + 1] = i1;
    gate[t * 2 + 0] = expf(lg[i0] - m) / den;
    gate[t * 2 + 1] = expf(lg[i1] - m) / den;
  }
}

// ---------------- grouping (verified) ----------------
__global__ void k_zero_counts(int* counts, int* cursor) {
  if (threadIdx.x < E_) {
    counts[threadIdx.x] = 0;
    cursor[threadIdx.x] = 0;
  }
}
__global__ void k_count(const int* __restrict__ eidx, int* __restrict__ counts) {
  int i = blockIdx.x * 256 + threadIdx.x;
  if (i < T_ * K_) atomicAdd(&counts[eidx[i]], 1);
}
__global__ void k_scan(const int* __restrict__ counts, int* __restrict__ offsets) {
  if (threadIdx.x == 0) {
    int a = 0;
    for (int e = 0; e < E_; ++e) {
      offsets[e] = a;
      a += counts[e];
    }
  }
}
__global__ void k_fill(const int* __restrict__ eidx, const float* __restrict__ gate,
                       const int* __restrict__ offsets, int* __restrict__ cursor,
                       int* __restrict__ rowtok, float* __restrict__ rowgate) {
  int i = blockIdx.x * 256 + threadIdx.x;
  if (i >= T_ * K_) return;
  int e = eidx[i];
  int p = atomicAdd(&cursor[e], 1);
  int r = offsets[e] + p;
  rowtok[r] = i >> 1;
  rowgate[r] = gate[i];
}

// ------- gemm1: 64x64 BK=32; A manual split (padded LDS), B async gload_lds (linear) -------
__global__ void k_mfma_gemm1(const float* __restrict__ h, const float* __restrict__ invr,
                             const float* __restrict__ eln,
                             const unsigned short* __restrict__ W1Thi,
                             const unsigned short* __restrict__ W1Tlo,
                             const int* __restrict__ counts, const int* __restrict__ offsets,
                             const int* __restrict__ rowtok, unsigned short* __restrict__ uHi,
                             unsigned short* __restrict__ uLo) {
  int e = blockIdx.z;
  int cnt = counts[e];
  int m0 = blockIdx.x * 64;
  if (m0 >= cnt) return;
  int n0 = blockIdx.y * 64;
  int base = offsets[e];

  __shared__ alignas(16) unsigned short Ah[64 * LDK];
  __shared__ alignas(16) unsigned short Al[64 * LDK];
  __shared__ alignas(16) unsigned short Bh[64 * LDL];
  __shared__ alignas(16) unsigned short Bl[64 * LDL];

  int tid = threadIdx.x;
  int lane = tid & 63;
  int wid = tid >> 6;
  int wr = wid >> 1, wc = wid & 1;
  int fr = lane & 15, fs = lane >> 4;

  // A manual staging: row am (0..63), k-chunk akq
  int am = tid >> 2;
  int akq = (tid & 3) * 8;
  int arow = m0 + am;
  bool av = arow < cnt;
  int tok = 0;
  float sc = 0.f;
  if (av) {
    tok = rowtok[base + arow];
    sc = invr[tok];
  }
  const float* hA = h + (size_t)tok * D_;
  const float* elnE = eln + (size_t)e * D_;

  // B async staging: wave stages rows [wid*16, wid*16+16), lane covers 16B
  int srow = wid * 16 + (lane >> 2);
  int skq = (lane & 3) * 8;
  const unsigned short* gBh = W1Thi + ((size_t)e * H_ + n0 + srow) * D_ + skq;
  const unsigned short* gBl = W1Tlo + ((size_t)e * H_ + n0 + srow) * D_ + skq;
  unsigned short* lBh = &Bh[wid * 16 * LDL];
  unsigned short* lBl = &Bl[wid * 16 * LDL];

  f32x4 zero4 = {0.f, 0.f, 0.f, 0.f};
  f32x4 acc[2][2];
  acc[0][0] = zero4; acc[0][1] = zero4; acc[1][0] = zero4; acc[1][1] = zero4;

  for (int k0 = 0; k0 < D_; k0 += 32) {
    gload_lds16(gBh + k0, lBh);
    gload_lds16(gBl + k0, lBl);
    {
      unsigned short ah8[8], al8[8];
      if (av) {
        const float* xp = hA + k0 + akq;
        const float* ep = elnE + k0 + akq;
#pragma unroll
        for (int q = 0; q < 8; ++q) split_bf(xp[q] * sc * ep[q], ah8[q], al8[q]);
      } else {
#pragma unroll
        for (int q = 0; q < 8; ++q) { ah8[q] = 0; al8[q] = 0; }
      }
      *(short8v*)&Ah[am * LDK + akq] = *(const short8v*)ah8;
      *(short8v*)&Al[am * LDK + akq] = *(const short8v*)al8;
    }
    __syncthreads();
    short8v a0h = *(const short8v*)&Ah[(wr * 32 + fr) * LDK + fs * 8];
    short8v a1h = *(const short8v*)&Ah[(wr * 32 + 16 + fr) * LDK + fs * 8];
    short8v a0l = *(const short8v*)&Al[(wr * 32 + fr) * LDK + fs * 8];
    short8v a1l = *(const short8v*)&Al[(wr * 32 + 16 + fr) * LDK + fs * 8];
    short8v b0h = *(const short8v*)&Bh[(wc * 32 + fr) * LDL + fs * 8];
    short8v b1h = *(const short8v*)&Bh[(wc * 32 + 16 + fr) * LDL + fs * 8];
    short8v b0l = *(const short8v*)&Bl[(wc * 32 + fr) * LDL + fs * 8];
    short8v b1l = *(const short8v*)&Bl[(wc * 32 + 16 + fr) * LDL + fs * 8];
    // (hi+lo)x(hi+lo) ~= hihi + hilo + lohi (drop lolo ~2^-34)
    acc[0][0] = __builtin_amdgcn_mfma_f32_16x16x32_bf16(a0h, b0h, acc[0][0], 0, 0, 0);
    acc[0][0] = __builtin_amdgcn_mfma_f32_16x16x32_bf16(a0h, b0l, acc[0][0], 0, 0, 0);
    acc[0][0] = __builtin_amdgcn_mfma_f32_16x16x32_bf16(a0l, b0h, acc[0][0], 0, 0, 0);
    acc[0][1] = __builtin_amdgcn_mfma_f32_16x16x32_bf16(a0h, b1h, acc[0][1], 0, 0, 0);
    acc[0][1] = __builtin_amdgcn_mfma_f32_16x16x32_bf16(a0h, b1l, acc[0][1], 0, 0, 0);
    acc[0][1] = __builtin_amdgcn_mfma_f32_16x16x32_bf16(a0l, b1h, acc[0][1], 0, 0, 0);
    acc[1][0] = __builtin_amdgcn_mfma_f32_16x16x32_bf16(a1h, b0h, acc[1][0], 0, 0, 0);
    acc[1][0] = __builtin_amdgcn_mfma_f32_16x16x32_bf16(a1h, b0l, acc[1][0], 0, 0, 0);
    acc[1][0] = __builtin_amdgcn_mfma_f32_16x16x32_bf16(a1l, b0h, acc[1][0], 0, 0, 0);
    acc[1][1] = __builtin_amdgcn_mfma_f32_16x16x32_bf16(a1h, b1h, acc[1][1], 0, 0, 0);
    acc[1][1] = __builtin_amdgcn_mfma_f32_16x16x32_bf16(a1h, b1l, acc[1][1], 0, 0, 0);
    acc[1][1] = __builtin_amdgcn_mfma_f32_16x16x32_bf16(a1l, b1h, acc[1][1], 0, 0, 0);
    __syncthreads();
  }
#pragma unroll
  for (int fi = 0; fi < 2; ++fi) {
#pragma unroll
    for (int i = 0; i < 4; ++i) {
      int row = m0 + wr * 32 + fi * 16 + fs * 4 + i;
      if (row < cnt) {
#pragma unroll
        for (int fj = 0; fj < 2; ++fj) {
          int col = n0 + wc * 32 + fj * 16 + fr;
          float g = gelu_f(acc[fi][fj][i]);
          unsigned short hi, lo;
          split_bf(g, hi, lo);
          size_t idx = (size_t)(base + row) * H_ + col;
          uHi[idx] = hi;
          uLo[idx] = lo;
        }
      }
    }
  }
}

// ------- gemm2: 64x64 BK=32; A and B both async gload_lds (linear LDS) -------
__global__ void k_mfma_gemm2(const unsigned short* __restrict__ uHi,
                             const unsigned short* __restrict__ uLo,
                             const unsigned short* __restrict__ W2Thi,
                             const unsigned short* __restrict__ W2Tlo,
                             const int* __restrict__ counts, const int* __restrict__ offsets,
                             const int* __restrict__ rowtok, const float* __restrict__ rowgate,
                             float* __restrict__ h) {
  int e = blockIdx.z;
  int cnt = counts[e];
  int m0 = blockIdx.x * 64;
  if (m0 >= cnt) return;
  int n0 = blockIdx.y * 64;
  int base = offsets[e];

  __shared__ alignas(16) unsigned short Ah[64 * LDL];
  __shared__ alignas(16) unsigned short Al[64 * LDL];
  __shared__ alignas(16) unsigned short Bh[64 * LDL];
  __shared__ alignas(16) unsigned short Bl[64 * LDL];

  int tid = threadIdx.x;
  int lane = tid & 63;
  int wid = tid >> 6;
  int wr = wid >> 1, wc = wid & 1;
  int fr = lane & 15, fs = lane >> 4;

  // async staging: wave stages rows [wid*16, wid*16+16) of each buffer
  int srow = wid * 16 + (lane >> 2);
  int skq = (lane & 3) * 8;
  int urow = base + m0 + srow;
  if (urow >= T_ * K_) urow = T_ * K_ - 1;  // rows >= cnt feed discarded outputs only
  const unsigned short* gAh = uHi + (size_t)urow * H_ + skq;
  const unsigned short* gAl = uLo + (size_t)urow * H_ + skq;
  const unsigned short* gBh = W2Thi + ((size_t)e * D_ + n0 + srow) * H_ + skq;
  const unsigned short* gBl = W2Tlo + ((size_t)e * D_ + n0 + srow) * H_ + skq;
  unsigned short* lAh = &Ah[wid * 16 * LDL];
  unsigned short* lAl = &Al[wid * 16 * LDL];
  unsigned short* lBh = &Bh[wid * 16 * LDL];
  unsigned short* lBl = &Bl[wid * 16 * LDL];

  f32x4 zero4 = {0.f, 0.f, 0.f, 0.f};
  f32x4 acc[2][2];
  acc[0][0] = zero4; acc[0][1] = zero4; acc[1][0] = zero4; acc[1][1] = zero4;

  for (int k0 = 0; k0 < H_; k0 += 32) {
    gload_lds16(gAh + k0, lAh);
    gload_lds16(gAl + k0, lAl);
    gload_lds16(gBh + k0, lBh);
    gload_lds16(gBl + k0, lBl);
    __syncthreads();
    short8v a0h = *(const short8v*)&Ah[(wr * 32 + fr) * LDL + fs * 8];
    short8v a1h = *(const short8v*)&Ah[(wr * 32 + 16 + fr) * LDL + fs * 8];
    short8v a0l = *(const short8v*)&Al[(wr * 32 + fr) * LDL + fs * 8];
    short8v a1l = *(const short8v*)&Al[(wr * 32 + 16 + fr) * LDL + fs * 8];
    short8v b0h = *(const short8v*)&Bh[(wc * 32 + fr) * LDL + fs * 8];
    short8v b1h = *(const short8v*)&Bh[(wc * 32 + 16 + fr) * LDL + fs * 8];
    short8v b0l = *(const short8v*)&Bl[(wc * 32 + fr) * LDL + fs * 8];
    short8v b1l = *(const short8v*)&Bl[(wc * 32 + 16 + fr) * LDL + fs * 8];
    acc[0][0] = __builtin_amdgcn_mfma_f32_16x16x32_bf16(a0h, b0h, acc[0][0], 0, 0, 0);
    acc[0][0] = __builtin_amdgcn_mfma_f32_16x16x32_bf16(a0h, b0l, acc[0][0], 0, 0, 0);
    acc[0][0] = __builtin_amdgcn_mfma_f32_16x16x32_bf16(a0l, b0h, acc[0][0], 0, 0, 0);
    acc[0][1] = __builtin_amdgcn_mfma_f32_16x16x32_bf16(a0h, b1h, acc[0][1], 0, 0, 0);
    acc[0][1] = __builtin_amdgcn_mfma_f32_16x16x32_bf16(a0h, b1l, acc[0][1], 0, 0, 0);
    acc[0][1] = __builtin_amdgcn_mfma_f32_16x16x32_bf16(a0l, b1h, acc[0][1], 0, 0, 0);
    acc[1][0] = __builtin_amdgcn_mfma_f32_16x16x32_bf16(a1h, b0h, acc[1][0], 0, 0, 0);
    acc[1][0] = __builtin_amdgcn_mfma_f32_16x16x32_bf16(a1h, b0l, acc[1][0], 0, 0, 0);
    acc[1][0] = __builtin_amdgcn_mfma_f32_16x16x32_bf16(a1l, b0h, acc[1][0], 0, 0, 0);
    acc[1][1] = __builtin_amdgcn_mfma_f32_16x16x32_bf16(a1h, b1h, acc[1][1], 0, 0, 0);
    acc[1][1] = __builtin_amdgcn_mfma_f32_16x16x32_bf16(a1h, b1l, acc[1][1], 0, 0, 0);
    acc[1][1] = __builtin_amdgcn_mfma_f32_16x16x32_bf16(a1l, b1h, acc[1][1], 0, 0, 0);
    __syncthreads();
  }
#pragma unroll
  for (int fi = 0; fi < 2; ++fi) {
#pragma unroll
    for (int i = 0; i < 4; ++i) {
      int row = m0 + wr * 32 + fi * 16 + fs * 4 + i;
      if (row < cnt) {
        int tok = rowtok[base + row];
        float g = rowgate[base + row];
        float* hp = h + (size_t)tok * D_;
#pragma unroll
        for (int fj = 0; fj < 2; ++fj) {
          int col = n0 + wc * 32 + fj * 16 + fr;
          atomicAdd(&hp[col], g * acc[fi][fj][i]);
        }
      }
    }
  }
}

// ---------------- final rmsnorm -> bf16 ----------------
__global__ void k_finalnorm(const float* __restrict__ h, const float* __restrict__ w,
                            unsigned short* __restrict__ fnb) {
  int t = blockIdx.x;
  int tid = threadIdx.x;
  const float* hp = h + (size_t)t * D_;
  float ss = 0.f;
  for (int d = tid; d < D_; d += 256) {
    float x = hp[d];
    ss += x * x;
  }
  __shared__ float s[256];
  s[tid] = ss;
  __syncthreads();
  for (int o = 128; o > 0; o >>= 1) {
    if (tid < o) s[tid] += s[tid + o];
    __syncthreads();
  }
  float ir = rsqrtf(s[0] / (float)D_ + EPS_);
  for (int d = tid; d < D_; d += 256) fnb[(size_t)t * D_ + d] = f2bf(hp[d] * ir * w[d]);
}

// ------- final GEMM: 64x64, single bf16; A async gload_lds, B manual convert -------
__global__ void k_mfma_final(const unsigned short* __restrict__ fnb,
                             const float* __restrict__ embed, float* __restrict__ out) {
  int m0 = blockIdx.x * 64;
  int n0 = blockIdx.y * 64;

  __shared__ alignas(16) unsigned short As[64 * LDL];
  __shared__ alignas(16) unsigned short Bs[64 * LDK];

  int tid = threadIdx.x;
  int lane = tid & 63;
  int wid = tid >> 6;
  int wr = wid >> 1, wc = wid & 1;
  int fr = lane & 15, fs = lane >> 4;

  // A async staging
  int srow = wid * 16 + (lane >> 2);
  int skq = (lane & 3) * 8;
  const unsigned short* gA = fnb + (size_t)(m0 + srow) * D_ + skq;
  unsigned short* lA = &As[wid * 16 * LDL];

  // B manual (f32 -> bf16 convert)
  int bn = tid >> 2;
  int bkq = (tid & 3) * 8;
  const float* eB = embed + (size_t)(n0 + bn) * D_;

  f32x4 zero4 = {0.f, 0.f, 0.f, 0.f};
  f32x4 acc[2][2];
  acc[0][0] = zero4; acc[0][1] = zero4; acc[1][0] = zero4; acc[1][1] = zero4;

  for (int k0 = 0; k0 < D_; k0 += 32) {
    gload_lds16(gA + k0, lA);
    {
      float4 x0 = *(const float4*)(eB + k0 + bkq);
      float4 x1 = *(const float4*)(eB + k0 + bkq + 4);
      unsigned short b8[8];
      b8[0] = f2bf(x0.x); b8[1] = f2bf(x0.y); b8[2] = f2bf(x0.z); b8[3] = f2bf(x0.w);
      b8[4] = f2bf(x1.x); b8[5] = f2bf(x1.y); b8[6] = f2bf(x1.z); b8[7] = f2bf(x1.w);
      *(short8v*)&Bs[bn * LDK + bkq] = *(const short8v*)b8;
    }
    __syncthreads();
    short8v a0 = *(const short8v*)&As[(wr * 32 + fr) * LDL + fs * 8];
    short8v a1 = *(const short8v*)&As[(wr * 32 + 16 + fr) * LDL + fs * 8];
    short8v b0 = *(const short8v*)&Bs[(wc * 32 + fr) * LDK + fs * 8];
    short8v b1 = *(const short8v*)&Bs[(wc * 32 + 16 + fr) * LDK + fs * 8];
    acc[0][0] = __builtin_amdgcn_mfma_f32_16x16x32_bf16(a0, b0, acc[0][0], 0, 0, 0);
    acc[0][1] = __builtin_amdgcn_mfma_f32_16x16x32_bf16(a0, b1, acc[0][1], 0, 0, 0);
    acc[1][0] = __builtin_amdgcn_mfma_f32_16x16x32_bf16(a1, b0, acc[1][0], 0, 0, 0);
    acc[1][1] = __builtin_amdgcn_mfma_f32_16x16x32_bf16(a1, b1, acc[1][1], 0, 0, 0);
    __syncthreads();
  }
#pragma unroll
  for (int fi = 0; fi < 2; ++fi) {
#pragma unroll
    for (int i = 0; i < 4; ++i) {
      int row = m0 + wr * 32 + fi * 16 + fs * 4 + i;
      float* op = out + (size_t)row * V_;
#pragma unroll
      for (int fj = 0; fj < 2; ++fj) {
        int col = n0 + wc * 32 + fj * 16 + fr;
        op[col] = acc[fi][fj][i];
      }
    }
  }
}

// ---------------- launch ----------------
extern "C" void kernel_launch(void* const* d_in, const int* in_sizes, int n_in,
                              void* d_out, int out_size, void* d_ws, size_t ws_size,
                              hipStream_t stream) {
  const int* ids = (const int*)d_in[0];
  const float* embed = (const float*)d_in[1];
  const float* router_ln = (const float*)d_in[2];
  const float* router_W = (const float*)d_in[3];
  const float* expert_ln = (const float*)d_in[4];
  const float* W1 = (const float*)d_in[5];
  const float* W2 = (const float*)d_in[6];
  const float* ln_out_w = (const float*)d_in[7];
  float* out = (float*)d_out;

  char* p = (char*)d_ws;
  auto carve = [&](size_t bytes) {
    char* r = p;
    p += (bytes + 255) & ~(size_t)255;
    return (void*)r;
  };
  float* h = (float*)carve((size_t)T_ * D_ * 4);
  unsigned short* fnb = (unsigned short*)carve((size_t)T_ * D_ * 2);
  unsigned short* uHi = (unsigned short*)carve((size_t)T_ * K_ * H_ * 2);
  unsigned short* uLo = (unsigned short*)carve((size_t)T_ * K_ * H_ * 2);
  unsigned short* w1thi = (unsigned short*)carve((size_t)E_ * D_ * H_ * 2);
  unsigned short* w1tlo = (unsigned short*)carve((size_t)E_ * D_ * H_ * 2);
  unsigned short* w2thi = (unsigned short*)carve((size_t)E_ * H_ * D_ * 2);
  unsigned short* w2tlo = (unsigned short*)carve((size_t)E_ * H_ * D_ * 2);
  float* invr = (float*)carve((size_t)T_ * 4);
  int* eidx = (int*)carve((size_t)T_ * K_ * 4);
  float* gate = (float*)carve((size_t)T_ * K_ * 4);
  int* rowtok = (int*)carve((size_t)T_ * K_ * 4);
  float* rowgate = (float*)carve((size_t)T_ * K_ * 4);
  int* counts = (int*)carve(256);
  int* offsets = (int*)carve(256);
  int* cursor = (int*)carve(256);

  // once per launch: split+transpose weights (constant across hops)
  k_split_transpose<<<dim3(D_ / 64, H_ / 64, E_), 256, 0, stream>>>(W1, w1thi, w1tlo, D_, H_);
  k_split_transpose<<<dim3(H_ / 64, D_ / 64, E_), 256, 0, stream>>>(W2, w2thi, w2tlo, H_, D_);

  k_gather<<<T_, 256, 0, stream>>>(ids, embed, h);

  for (int hop = 0; hop < NHOPS_; ++hop) {
    const float* rln = router_ln + (size_t)hop * D_;
    const float* rW = router_W + (size_t)hop * D_ * E_;
    k_router<<<T_, 256, 0, stream>>>(h, rln, rW, invr, eidx, gate);
    k_zero_counts<<<1, 64, 0, stream>>>(counts, cursor);
    k_count<<<(T_ * K_) / 256, 256, 0, stream>>>(eidx, counts);
    k_scan<<<1, 64, 0, stream>>>(counts, offsets);
    k_fill<<<(T_ * K_) / 256, 256, 0, stream>>>(eidx, gate, offsets, cursor, rowtok, rowgate);
    k_mfma_gemm1<<<dim3(T_ * K_ / 64, H_ / 64, E_), 256, 0, stream>>>(
        h, invr, expert_ln, w1thi, w1tlo, counts, offsets, rowtok, uHi, uLo);
    k_mfma_gemm2<<<dim3(T_ * K_ / 64, D_ / 64, E_), 256, 0, stream>>>(
        uHi, uLo, w2thi, w2tlo, counts, offsets, rowtok, rowgate, h);
  }

  k_finalnorm<<<T_, 256, 0, stream>>>(h, ln_out_w, fnb);
  k_mfma_final<<<dim3(T_ / 64, V_ / 64), 256, 0, stream>>>(fnb, embed, out);
}